// Round 7
// baseline (364.000 us; speedup 1.0000x reference)
//
#include <hip/hip_runtime.h>

typedef unsigned short u16;
typedef __attribute__((ext_vector_type(8))) short bf16x8;
typedef __attribute__((ext_vector_type(8))) unsigned short u16x8;
typedef __attribute__((ext_vector_type(4))) float f32x4;

__device__ __forceinline__ u16 f2b(float f) {
  unsigned u = __float_as_uint(f);
  u += 0x7FFFu + ((u >> 16) & 1u);
  return (u16)(u >> 16);
}
__device__ __forceinline__ float b2f(u16 v) { return __uint_as_float(((unsigned)v) << 16); }
__device__ __forceinline__ float sigm(float x) { return 1.0f / (1.0f + __expf(-x)); }
__device__ __forceinline__ float tanh_f(float x) { return 1.0f - 2.0f / (__expf(2.0f * x) + 1.0f); }

// LDS address (bytes) for (row, colByte) in a [rows][32 u16] tile; 64 B/row,
// XOR row-pair into the 16B-slot bits: read & write use the same map.
__device__ __forceinline__ int swb(int row, int cb) {
  return row * 64 + (cb ^ ((((row >> 1) & 3)) << 4));
}

// pack 8 f32 (two float4) -> one 16B LDS write
__device__ __forceinline__ void wr8f(u16* dst, float4 a, float4 b) {
  u16x8 v;
  v[0] = f2b(a.x); v[1] = f2b(a.y); v[2] = f2b(a.z); v[3] = f2b(a.w);
  v[4] = f2b(b.x); v[5] = f2b(b.y); v[6] = f2b(b.z); v[7] = f2b(b.w);
  *reinterpret_cast<u16x8*>(dst) = v;
}

// ===================== GEMM z/r: [8192 x 2048] over K=2048 ======================
// A[i][k] = bf16(k<1024 ? x[i][k] : h[i][k-1024]); B rows: n<1024 -> [Wwz|Wuz], else [Wwr|Wur].
// BM=256 BN=256 BK=32 NT=64. 8 waves 2Mx4N, wave tile 128x64, acc[8][4].
__global__ __launch_bounds__(512, 2) void gemm_zr(const float* __restrict__ x,
                                                  const float* __restrict__ h,
                                                  const float* __restrict__ Wwz,
                                                  const float* __restrict__ Wuz,
                                                  const float* __restrict__ Wwr,
                                                  const float* __restrict__ Wur,
                                                  float* __restrict__ zout,
                                                  u16* __restrict__ rhb) {
  __shared__ u16 A0[8192], A1[8192], B0[8192], B1[8192];   // 16 KB each
  const int b = blockIdx.x;
  const int wg = (b & 7) * 32 + (b >> 3);
  const int mb = wg >> 3, nb = wg & 7;
  const int m0 = mb * 256, n0 = nb * 256;

  const int tid = threadIdx.x;
  const int lane = tid & 63;
  const int wid = tid >> 6;
  const int wrr = wid >> 2, wcc = wid & 3;
  // staging coords: thread covers (row rS, 16B slot sS) and (row rS+128, slot sS), for A and B
  const int rS = tid >> 2;
  const int sS = (tid & 3) * 16;          // byte slot
  const int kcs = (tid & 3) * 8;          // f32 col offset of slot
  // fragment coords
  const int frow = lane & 15;
  const int fcb = (lane >> 4) * 16;       // byte k-part

  f32x4 acc[8][4];
#pragma unroll
  for (int m = 0; m < 8; ++m)
#pragma unroll
    for (int n = 0; n < 4; ++n) acc[m][n] = (f32x4){0.f, 0.f, 0.f, 0.f};

  const bool isz = (n0 < 1024);

#define ZR_LOAD(T, a0, a1, a2, a3, b0, b1, b2, b3)                                   \
  {                                                                                  \
    const int k1 = (T) * 32;                                                         \
    const float* Asrc = ((k1 < 1024) ? x : h) + (size_t)(m0 + rS) * 1024 +           \
                        (k1 & 1023) + kcs;                                           \
    a0 = *reinterpret_cast<const float4*>(Asrc);                                     \
    a1 = *reinterpret_cast<const float4*>(Asrc + 4);                                 \
    a2 = *reinterpret_cast<const float4*>(Asrc + 128 * 1024);                        \
    a3 = *reinterpret_cast<const float4*>(Asrc + 128 * 1024 + 4);                    \
    const float* Wz = (k1 < 1024) ? Wwz : Wuz;                                       \
    const float* Wr = (k1 < 1024) ? Wwr : Wur;                                       \
    const float* Bb = isz ? (Wz + (size_t)n0 * 1024) : (Wr + (size_t)(n0 - 1024) * 1024); \
    const float* Bsrc = Bb + (size_t)rS * 1024 + (k1 & 1023) + kcs;                  \
    b0 = *reinterpret_cast<const float4*>(Bsrc);                                     \
    b1 = *reinterpret_cast<const float4*>(Bsrc + 4);                                 \
    b2 = *reinterpret_cast<const float4*>(Bsrc + 128 * 1024);                        \
    b3 = *reinterpret_cast<const float4*>(Bsrc + 128 * 1024 + 4);                    \
  }

#define ZR_WRITE(Aw, Bw, a0, a1, a2, a3, b0, b1, b2, b3)                             \
  {                                                                                  \
    wr8f((u16*)((char*)Aw + swb(rS, sS)), a0, a1);                                   \
    wr8f((u16*)((char*)Aw + swb(rS + 128, sS)), a2, a3);                             \
    wr8f((u16*)((char*)Bw + swb(rS, sS)), b0, b1);                                   \
    wr8f((u16*)((char*)Bw + swb(rS + 128, sS)), b2, b3);                             \
  }

#define ZR_TILE(T, Ar, Br, Aw, Bw)                                                   \
  {                                                                                  \
    float4 a0, a1, a2, a3, b0, b1, b2, b3;                                           \
    const bool pf = ((T) + 1 < 64);                                                  \
    if (pf) ZR_LOAD((T) + 1, a0, a1, a2, a3, b0, b1, b2, b3);                        \
    bf16x8 af[8];                                                                    \
    _Pragma("unroll") for (int m = 0; m < 8; ++m)                                    \
        af[m] = *reinterpret_cast<const bf16x8*>(                                    \
            (char*)Ar + swb(wrr * 128 + m * 16 + frow, fcb));                        \
    _Pragma("unroll") for (int n = 0; n < 4; ++n) {                                  \
      bf16x8 bf = *reinterpret_cast<const bf16x8*>(                                  \
          (char*)Br + swb(wcc * 64 + n * 16 + frow, fcb));                           \
      _Pragma("unroll") for (int m = 0; m < 8; ++m)                                  \
          acc[m][n] = __builtin_amdgcn_mfma_f32_16x16x32_bf16(af[m], bf, acc[m][n], 0, 0, 0); \
    }                                                                                \
    if (pf) ZR_WRITE(Aw, Bw, a0, a1, a2, a3, b0, b1, b2, b3);                        \
    __syncthreads();                                                                 \
  }

  // prologue: stage tile 0 into A0/B0
  {
    float4 a0, a1, a2, a3, b0, b1, b2, b3;
    ZR_LOAD(0, a0, a1, a2, a3, b0, b1, b2, b3);
    ZR_WRITE(A0, B0, a0, a1, a2, a3, b0, b1, b2, b3);
    __syncthreads();
  }
  for (int t = 0; t < 64; t += 2) {
    ZR_TILE(t, A0, B0, A1, B1);
    ZR_TILE(t + 1, A1, B1, A0, B0);
  }
#undef ZR_TILE
#undef ZR_WRITE
#undef ZR_LOAD

  // epilogue
  const int rbase = m0 + wrr * 128 + ((lane >> 4) << 2);
  const int cbase = n0 + wcc * 64 + (lane & 15);
#pragma unroll
  for (int m = 0; m < 8; ++m) {
#pragma unroll
    for (int n = 0; n < 4; ++n) {
      const int col = cbase + n * 16;
#pragma unroll
      for (int j = 0; j < 4; ++j) {
        const int row = rbase + m * 16 + j;
        const float v = acc[m][n][j];
        if (isz) {
          zout[(size_t)row * 1024 + col] = sigm(v);
        } else {
          const size_t idx = (size_t)row * 1024 + (col - 1024);
          rhb[idx] = f2b(sigm(v) * h[idx]);
        }
      }
    }
  }
}

// ============== 256x128 core (K=1024, NT=32) for gemm_w / gemm2 ==============
// 8 waves 2Mx4N, wave tile 128x32, acc[8][2]. A rows 256 (2 passes), B rows 128 (1 pass).
#define C2_GEOM()                                   \
  const int tid = threadIdx.x;                      \
  const int lane = tid & 63;                        \
  const int wid = tid >> 6;                         \
  const int wrr = wid >> 2, wcc = wid & 3;          \
  const int rS = tid >> 2;                          \
  const int sS = (tid & 3) * 16;                    \
  const int kcs = (tid & 3) * 8;                    \
  const int frow = lane & 15;                       \
  const int fcb = (lane >> 4) * 16;

#define C2_MFMA(Ar, Br)                                                              \
  {                                                                                  \
    bf16x8 af[8];                                                                    \
    _Pragma("unroll") for (int m = 0; m < 8; ++m)                                    \
        af[m] = *reinterpret_cast<const bf16x8*>(                                    \
            (char*)Ar + swb(wrr * 128 + m * 16 + frow, fcb));                        \
    _Pragma("unroll") for (int n = 0; n < 2; ++n) {                                  \
      bf16x8 bf = *reinterpret_cast<const bf16x8*>(                                  \
          (char*)Br + swb(wcc * 32 + n * 16 + frow, fcb));                           \
      _Pragma("unroll") for (int m = 0; m < 8; ++m)                                  \
          acc[m][n] = __builtin_amdgcn_mfma_f32_16x16x32_bf16(af[m], bf, acc[m][n], 0, 0, 0); \
    }                                                                                \
  }

// GEMM w: xwb = x @ Ww^T (bf16 out). grid 256.
__global__ __launch_bounds__(512, 2) void gemm_w(const float* __restrict__ x,
                                                 const float* __restrict__ Ww,
                                                 u16* __restrict__ xwb) {
  __shared__ u16 A0[8192], A1[8192], B0[4096], B1[4096];
  const int b = blockIdx.x;
  const int wg = (b & 7) * 32 + (b >> 3);
  const int mb = wg >> 3, nb = wg & 7;
  const int m0 = mb * 256, n0 = nb * 128;
  C2_GEOM();
  f32x4 acc[8][2];
#pragma unroll
  for (int m = 0; m < 8; ++m)
#pragma unroll
    for (int n = 0; n < 2; ++n) acc[m][n] = (f32x4){0.f, 0.f, 0.f, 0.f};

#define W_LOAD(T, a0, a1, a2, a3, b0, b1)                                            \
  {                                                                                  \
    const int k1 = (T) * 32;                                                         \
    const float* Asrc = x + (size_t)(m0 + rS) * 1024 + k1 + kcs;                     \
    a0 = *reinterpret_cast<const float4*>(Asrc);                                     \
    a1 = *reinterpret_cast<const float4*>(Asrc + 4);                                 \
    a2 = *reinterpret_cast<const float4*>(Asrc + 128 * 1024);                        \
    a3 = *reinterpret_cast<const float4*>(Asrc + 128 * 1024 + 4);                    \
    const float* Bsrc = Ww + (size_t)(n0 + rS) * 1024 + k1 + kcs;                    \
    b0 = *reinterpret_cast<const float4*>(Bsrc);                                     \
    b1 = *reinterpret_cast<const float4*>(Bsrc + 4);                                 \
  }
#define W_WRITE(Aw, Bw, a0, a1, a2, a3, b0, b1)                                      \
  {                                                                                  \
    wr8f((u16*)((char*)Aw + swb(rS, sS)), a0, a1);                                   \
    wr8f((u16*)((char*)Aw + swb(rS + 128, sS)), a2, a3);                             \
    if (rS < 128) wr8f((u16*)((char*)Bw + swb(rS, sS)), b0, b1);                     \
  }
#define W_TILE(T, Ar, Br, Aw, Bw)                                                    \
  {                                                                                  \
    float4 a0, a1, a2, a3, b0, b1;                                                   \
    const bool pf = ((T) + 1 < 32);                                                  \
    if (pf) W_LOAD((T) + 1, a0, a1, a2, a3, b0, b1);                                 \
    C2_MFMA(Ar, Br);                                                                 \
    if (pf) W_WRITE(Aw, Bw, a0, a1, a2, a3, b0, b1);                                 \
    __syncthreads();                                                                 \
  }
  {
    float4 a0, a1, a2, a3, b0, b1;
    W_LOAD(0, a0, a1, a2, a3, b0, b1);
    W_WRITE(A0, B0, a0, a1, a2, a3, b0, b1);
    __syncthreads();
  }
  for (int t = 0; t < 32; t += 2) {
    W_TILE(t, A0, B0, A1, B1);
    W_TILE(t + 1, A1, B1, A0, B0);
  }
#undef W_TILE
#undef W_WRITE
#undef W_LOAD

  const int rbase = m0 + wrr * 128 + ((lane >> 4) << 2);
  const int cbase = n0 + wcc * 32 + (lane & 15);
#pragma unroll
  for (int m = 0; m < 8; ++m)
#pragma unroll
    for (int n = 0; n < 2; ++n)
#pragma unroll
      for (int j = 0; j < 4; ++j)
        xwb[(size_t)(rbase + m * 16 + j) * 1024 + cbase + n * 16] = f2b(acc[m][n][j]);
}

// GEMM2: C2 = rhb @ Wu^T; out = z*h + (1-z)*tanh(C2 + xw). grid 256.
__global__ __launch_bounds__(512, 2) void gemm2_k(const u16* __restrict__ rhb,
                                                  const float* __restrict__ Wu,
                                                  const float* __restrict__ h,
                                                  const u16* __restrict__ xwb,
                                                  float* __restrict__ out) {
  __shared__ u16 A0[8192], A1[8192], B0[4096], B1[4096];
  const int b = blockIdx.x;
  const int wg = (b & 7) * 32 + (b >> 3);
  const int mb = wg >> 3, nb = wg & 7;
  const int m0 = mb * 256, n0 = nb * 128;
  C2_GEOM();
  f32x4 acc[8][2];
#pragma unroll
  for (int m = 0; m < 8; ++m)
#pragma unroll
    for (int n = 0; n < 2; ++n) acc[m][n] = (f32x4){0.f, 0.f, 0.f, 0.f};

#define G2_LOAD(T, a0, a1, b0, b1)                                                   \
  {                                                                                  \
    const int k1 = (T) * 32;                                                         \
    const u16* Asrc = rhb + (size_t)(m0 + rS) * 1024 + k1 + kcs;                     \
    a0 = *reinterpret_cast<const u16x8*>(Asrc);                                      \
    a1 = *reinterpret_cast<const u16x8*>(Asrc + 128 * 1024);                         \
    const float* Bsrc = Wu + (size_t)(n0 + rS) * 1024 + k1 + kcs;                    \
    b0 = *reinterpret_cast<const float4*>(Bsrc);                                     \
    b1 = *reinterpret_cast<const float4*>(Bsrc + 4);                                 \
  }
#define G2_WRITE(Aw, Bw, a0, a1, b0, b1)                                             \
  {                                                                                  \
    *reinterpret_cast<u16x8*>((char*)Aw + swb(rS, sS)) = a0;                         \
    *reinterpret_cast<u16x8*>((char*)Aw + swb(rS + 128, sS)) = a1;                   \
    if (rS < 128) wr8f((u16*)((char*)Bw + swb(rS, sS)), b0, b1);                     \
  }
#define G2_TILE(T, Ar, Br, Aw, Bw)                                                   \
  {                                                                                  \
    u16x8 a0, a1; float4 b0, b1;                                                     \
    const bool pf = ((T) + 1 < 32);                                                  \
    if (pf) G2_LOAD((T) + 1, a0, a1, b0, b1);                                        \
    C2_MFMA(Ar, Br);                                                                 \
    if (pf) G2_WRITE(Aw, Bw, a0, a1, b0, b1);                                        \
    __syncthreads();                                                                 \
  }
  {
    u16x8 a0, a1; float4 b0, b1;
    G2_LOAD(0, a0, a1, b0, b1);
    G2_WRITE(A0, B0, a0, a1, b0, b1);
    __syncthreads();
  }
  for (int t = 0; t < 32; t += 2) {
    G2_TILE(t, A0, B0, A1, B1);
    G2_TILE(t + 1, A1, B1, A0, B0);
  }
#undef G2_TILE
#undef G2_WRITE
#undef G2_LOAD

  const int rbase = m0 + wrr * 128 + ((lane >> 4) << 2);
  const int cbase = n0 + wcc * 32 + (lane & 15);
#pragma unroll
  for (int m = 0; m < 8; ++m) {
#pragma unroll
    for (int n = 0; n < 2; ++n) {
      const int col = cbase + n * 16;
#pragma unroll
      for (int j = 0; j < 4; ++j) {
        const int row = rbase + m * 16 + j;
        const size_t idx = (size_t)row * 1024 + col;
        const float z = out[idx];
        const float hv = h[idx];
        const float ht = tanh_f(acc[m][n][j] + b2f(xwb[idx]));
        out[idx] = z * hv + (1.0f - z) * ht;
      }
    }
  }
}

// ---------- launch ----------
extern "C" void kernel_launch(void* const* d_in, const int* in_sizes, int n_in,
                              void* d_out, int out_size, void* d_ws, size_t ws_size,
                              hipStream_t stream) {
  const float* x   = (const float*)d_in[0];
  const float* h   = (const float*)d_in[1];
  const float* Wwz = (const float*)d_in[2];
  const float* Wuz = (const float*)d_in[3];
  const float* Wwr = (const float*)d_in[4];
  const float* Wur = (const float*)d_in[5];
  const float* Wu  = (const float*)d_in[6];
  const float* Ww  = (const float*)d_in[7];
  float* out = (float*)d_out;

  char* ws = (char*)d_ws;
  u16* rhb = (u16*)(ws);               // 8192*1024*2 = 16,777,216
  u16* xwb = (u16*)(ws + 16777216);    // 8192*1024*2 = 16,777,216

  gemm_zr<<<256, 512, 0, stream>>>(x, h, Wwz, Wuz, Wwr, Wur, out, rhb);
  gemm_w<<<256, 512, 0, stream>>>(x, Ww, xwb);
  gemm2_k<<<256, 512, 0, stream>>>(rhb, Wu, h, xwb, out);
}

// Round 8
// 313.047 us; speedup vs baseline: 1.1628x; 1.1628x over previous
//
#include <hip/hip_runtime.h>

typedef unsigned short u16;
typedef __attribute__((ext_vector_type(8))) short bf16x8;
typedef __attribute__((ext_vector_type(8))) unsigned short u16x8;
typedef __attribute__((ext_vector_type(4))) float f32x4;

// ---------- helpers ----------
__device__ __forceinline__ u16 f2b(float f) {
  unsigned u = __float_as_uint(f);
  u += 0x7FFFu + ((u >> 16) & 1u);   // RNE to bf16
  return (u16)(u >> 16);
}
__device__ __forceinline__ float sigm(float x) { return 1.0f / (1.0f + __expf(-x)); }
__device__ __forceinline__ float tanh_f(float x) { return 1.0f - 2.0f / (__expf(2.0f * x) + 1.0f); }

__device__ __forceinline__ void cp16(const u16* g, u16* l) {
  __builtin_amdgcn_global_load_lds(
      (const __attribute__((address_space(1))) unsigned int*)g,
      (__attribute__((address_space(3))) unsigned int*)l, 16, 0, 0);
}

// swizzle involution on bytes within an 8KB round (64 rows x 128B)
__device__ __forceinline__ int swz(int b) {
  return b ^ (((b >> 7) & 3) << 5) ^ (((b >> 9) & 1) << 4);
}

__device__ __forceinline__ u16x8 cvt8(float4 a, float4 b) {
  u16x8 v;
  v[0] = f2b(a.x); v[1] = f2b(a.y); v[2] = f2b(a.z); v[3] = f2b(a.w);
  v[4] = f2b(b.x); v[5] = f2b(b.y); v[6] = f2b(b.z); v[7] = f2b(b.w);
  return v;
}

// ---------- pack kernels ----------
// xhb[i] = [x_i | h_i] bf16 (8192x2048); A2 right half: A2[i][1024+k] = bf16(x[i][k])
__global__ __launch_bounds__(256) void pack_xh(const float* __restrict__ x,
                                               const float* __restrict__ h,
                                               u16* __restrict__ xhb,
                                               u16* __restrict__ A2) {
  int idx = blockIdx.x * 256 + threadIdx.x;   // 2M threads, 8 elems each
  int row = idx >> 8;
  int k = (idx & 255) << 3;
  const float* src = (k < 1024) ? (x + (size_t)row * 1024 + k)
                                : (h + (size_t)row * 1024 + (k - 1024));
  float4 a = *reinterpret_cast<const float4*>(src);
  float4 b = *reinterpret_cast<const float4*>(src + 4);
  u16x8 v = cvt8(a, b);
  *reinterpret_cast<u16x8*>(xhb + ((size_t)row << 11) + k) = v;
  if (k < 1024)
    *reinterpret_cast<u16x8*>(A2 + ((size_t)row << 11) + 1024 + k) = v;
}

// W1b[2048][2048]: rows 0..1023 [Wwz|Wuz], 1024..2047 [Wwr|Wur].
// W2b[1024][2048]: [Wu|Ww].
__global__ __launch_bounds__(256) void pack_W(const float* __restrict__ Wwz,
                                              const float* __restrict__ Wuz,
                                              const float* __restrict__ Wwr,
                                              const float* __restrict__ Wur,
                                              const float* __restrict__ Wu,
                                              const float* __restrict__ Ww,
                                              u16* __restrict__ W1b,
                                              u16* __restrict__ W2b) {
  int idx = blockIdx.x * 256 + threadIdx.x;   // 768K threads
  const float* src;
  u16* dst;
  if (idx < 524288) {                         // W1b: 4M elems / 8
    int row = idx >> 8;
    int k = (idx & 255) << 3;
    const float* lo = (row < 1024) ? Wwz : Wwr;
    const float* hi = (row < 1024) ? Wuz : Wur;
    int n = row & 1023;
    src = (k < 1024) ? (lo + (size_t)n * 1024 + k) : (hi + (size_t)n * 1024 + (k - 1024));
    dst = W1b + ((size_t)row << 11) + k;
  } else {                                    // W2b: 2M elems / 8
    int j = idx - 524288;
    int row = j >> 8;
    int k = (j & 255) << 3;
    src = (k < 1024) ? (Wu + (size_t)row * 1024 + k) : (Ww + (size_t)row * 1024 + (k - 1024));
    dst = W2b + ((size_t)row << 11) + k;
  }
  float4 a = *reinterpret_cast<const float4*>(src);
  float4 b = *reinterpret_cast<const float4*>(src + 4);
  *reinterpret_cast<u16x8*>(dst) = cvt8(a, b);
}

// ---------- 256x128 core (R5, measured best): 4-phase/K-tile, double-buffered DMA ----------
// C[256x128] = A[256xK] @ B[128xK]^T, row-major bf16, pre-offset. 8 waves 4Mx2N, wave 64x64.
__device__ __forceinline__ void body(int t, int NT,
                                     const u16* __restrict__ Ag, const u16* __restrict__ Bg,
                                     int lda, int ldb,
                                     const u16* Ar, const u16* Br, u16* Aw, u16* Bw,
                                     int r0, int c2, int arl0, int arl1,
                                     int wr, int wc, int tid, f32x4 acc[4][4]) {
  const int ab = wr * 4096;   // wave's A round (u16 units)
  const int bb = wc * 4096;   // wave's B round
  // ---- phase q0 ----
  bf16x8 af0[2][2], bfr[4][2];
#pragma unroll
  for (int mm = 0; mm < 2; ++mm) {
    af0[mm][0] = *reinterpret_cast<const bf16x8*>(Ar + ab + mm * 1024 + arl0);
    af0[mm][1] = *reinterpret_cast<const bf16x8*>(Ar + ab + mm * 1024 + arl1);
  }
#pragma unroll
  for (int nf = 0; nf < 4; ++nf) {
    bfr[nf][0] = *reinterpret_cast<const bf16x8*>(Br + bb + nf * 1024 + arl0);
    bfr[nf][1] = *reinterpret_cast<const bf16x8*>(Br + bb + nf * 1024 + arl1);
  }
  if (t + 1 < NT) {
    const u16* g0 = Ag + (size_t)r0 * lda + c2 + (size_t)(t + 1) * 64;
    u16* l0 = Aw + tid * 8;
    cp16(g0, l0); cp16(g0 + (size_t)64 * lda, l0 + 4096);
    const u16* g1 = Ag + (size_t)(128 + r0) * lda + c2 + (size_t)(t + 1) * 64;
    u16* l1 = Aw + 8192 + tid * 8;
    cp16(g1, l1); cp16(g1 + (size_t)64 * lda, l1 + 4096);
  }
  __builtin_amdgcn_s_barrier();
  __builtin_amdgcn_s_setprio(1);
#pragma unroll
  for (int mm = 0; mm < 2; ++mm)
#pragma unroll
    for (int nf = 0; nf < 4; ++nf)
#pragma unroll
      for (int ks = 0; ks < 2; ++ks)
        acc[mm][nf] = __builtin_amdgcn_mfma_f32_16x16x32_bf16(
            af0[mm][ks], bfr[nf][ks], acc[mm][nf], 0, 0, 0);
  __builtin_amdgcn_s_setprio(0);
  __builtin_amdgcn_s_barrier();
  // ---- phase q1 ----
  bf16x8 af1[2][2];
#pragma unroll
  for (int mm = 0; mm < 2; ++mm) {
    af1[mm][0] = *reinterpret_cast<const bf16x8*>(Ar + ab + (2 + mm) * 1024 + arl0);
    af1[mm][1] = *reinterpret_cast<const bf16x8*>(Ar + ab + (2 + mm) * 1024 + arl1);
  }
  if (t + 2 < NT) {
    const u16* g = Bg + (size_t)r0 * ldb + c2 + (size_t)(t + 2) * 64;
    u16* l = Bw + tid * 8;
    cp16(g, l); cp16(g + (size_t)64 * ldb, l + 4096);
    asm volatile("s_waitcnt vmcnt(2)" ::: "memory");   // A(t+1) landed; B(t+2) flying
  } else {
    asm volatile("s_waitcnt vmcnt(0)" ::: "memory");
  }
  __builtin_amdgcn_s_barrier();
  __builtin_amdgcn_s_setprio(1);
#pragma unroll
  for (int mm = 0; mm < 2; ++mm)
#pragma unroll
    for (int nf = 0; nf < 4; ++nf)
#pragma unroll
      for (int ks = 0; ks < 2; ++ks)
        acc[2 + mm][nf] = __builtin_amdgcn_mfma_f32_16x16x32_bf16(
            af1[mm][ks], bfr[nf][ks], acc[2 + mm][nf], 0, 0, 0);
  __builtin_amdgcn_s_setprio(0);
  __builtin_amdgcn_s_barrier();
}

__device__ __forceinline__ void core(const u16* __restrict__ Ag, const u16* __restrict__ Bg,
                                     int lda, int ldb, int NT,
                                     u16* As0, u16* As1, u16* Bs0, u16* Bs1,
                                     f32x4 acc[4][4]) {
  const int tid = threadIdx.x;
  const int lane = tid & 63;
  const int wid = tid >> 6;
  const int wr = wid >> 1;   // 0..3 (M)
  const int wc = wid & 1;    // 0..1 (N)

  const int plo = tid * 16;
  const int olo = swz(plo);
  const int r0 = olo >> 7;
  const int c2 = (olo & 127) >> 1;

  const int frow = lane & 15;
  const int fcb = (lane >> 4) * 16;
  const int mask = ((frow & 3) << 5) | (((frow >> 2) & 1) << 4);
  const int arl0 = (frow * 128 + ((fcb + 0) ^ mask)) >> 1;
  const int arl1 = (frow * 128 + ((fcb + 64) ^ mask)) >> 1;

  // prologue: A(0)->As0, B(0)->Bs0, B(1)->Bs1
  {
    const u16* g; u16* l;
    g = Ag + (size_t)r0 * lda + c2;          l = As0 + tid * 8;        cp16(g, l); cp16(g + (size_t)64 * lda, l + 4096);
    g = Ag + (size_t)(128 + r0) * lda + c2;  l = As0 + 8192 + tid * 8; cp16(g, l); cp16(g + (size_t)64 * lda, l + 4096);
    g = Bg + (size_t)r0 * ldb + c2;          l = Bs0 + tid * 8;        cp16(g, l); cp16(g + (size_t)64 * ldb, l + 4096);
    g = Bg + (size_t)r0 * ldb + c2 + 64;     l = Bs1 + tid * 8;        cp16(g, l); cp16(g + (size_t)64 * ldb, l + 4096);
  }
  asm volatile("s_waitcnt vmcnt(2)" ::: "memory");   // A(0),B(0) landed; B(1) in flight
  __builtin_amdgcn_s_barrier();

  for (int u = 0; u < NT; u += 2) {
    body(u,     NT, Ag, Bg, lda, ldb, As0, Bs0, As1, Bs0, r0, c2, arl0, arl1, wr, wc, tid, acc);
    body(u + 1, NT, Ag, Bg, lda, ldb, As1, Bs1, As0, Bs1, r0, c2, arl0, arl1, wr, wc, tid, acc);
  }
}

#define CORE_PRE()                                           \
  __shared__ u16 As0[16384];                                 \
  __shared__ u16 As1[16384];                                 \
  __shared__ u16 Bs0[8192];                                  \
  __shared__ u16 Bs1[8192];                                  \
  f32x4 acc[4][4];                                           \
  _Pragma("unroll") for (int m = 0; m < 4; ++m)              \
  _Pragma("unroll") for (int n = 0; n < 4; ++n)              \
      acc[m][n] = (f32x4){0.f, 0.f, 0.f, 0.f};

// GEMM z/r: [8192 x 2048] = xhb @ W1b^T. grid 512. Writes z->out, rh->A2 left half (bf16).
__global__ __launch_bounds__(512) void gemm_zr(const u16* __restrict__ xhb,
                                               const u16* __restrict__ W1b,
                                               const float* __restrict__ h,
                                               float* __restrict__ zout,
                                               u16* __restrict__ A2) {
  int b = blockIdx.x;
  int wg = (b & 7) * 64 + (b >> 3);   // XCD chunk of 64 wgs
  int mb = wg >> 4, nb = wg & 15;     // m-major within chunk
  const int m0 = mb * 256, n0 = nb * 128;
  CORE_PRE();
  core(xhb + (size_t)m0 * 2048, W1b + (size_t)n0 * 2048, 2048, 2048, 32,
       As0, As1, Bs0, Bs1, acc);

  const int lane = threadIdx.x & 63;
  const int wid = threadIdx.x >> 6;
  const int wr = wid >> 1, wc = wid & 1;
  const int rbase = m0 + wr * 64 + ((lane >> 4) << 2);
  const int cbase = n0 + wc * 64 + (lane & 15);
  const int isz = (n0 < 1024);
#pragma unroll
  for (int m = 0; m < 4; ++m) {
#pragma unroll
    for (int nf = 0; nf < 4; ++nf) {
      const int col = cbase + nf * 16;
#pragma unroll
      for (int j = 0; j < 4; ++j) {
        const int row = rbase + m * 16 + j;
        const float v = acc[m][nf][j];
        if (isz) {
          zout[(size_t)row * 1024 + col] = sigm(v);
        } else {
          const int c = col - 1024;
          const float rh = sigm(v) * h[(size_t)row * 1024 + c];
          A2[((size_t)row << 11) + c] = f2b(rh);   // A2 left half
        }
      }
    }
  }
}

// GEMM2: [8192 x 1024] = A2([rh|x]) @ W2b([Wu|Ww])^T, K=2048. grid 256.
// out = z*h + (1-z)*tanh(C2)
__global__ __launch_bounds__(512) void gemm2_k(const u16* __restrict__ A2,
                                               const u16* __restrict__ W2b,
                                               const float* __restrict__ h,
                                               float* __restrict__ out) {  // holds z
  int b = blockIdx.x;
  int wg = (b & 7) * 32 + (b >> 3);
  int mb = wg >> 3, nb = wg & 7;
  const int m0 = mb * 256, n0 = nb * 128;
  CORE_PRE();
  core(A2 + (size_t)m0 * 2048, W2b + (size_t)n0 * 2048, 2048, 2048, 32,
       As0, As1, Bs0, Bs1, acc);

  const int lane = threadIdx.x & 63;
  const int wid = threadIdx.x >> 6;
  const int wr = wid >> 1, wc = wid & 1;
  const int rbase = m0 + wr * 64 + ((lane >> 4) << 2);
  const int cbase = n0 + wc * 64 + (lane & 15);
#pragma unroll
  for (int m = 0; m < 4; ++m) {
#pragma unroll
    for (int nf = 0; nf < 4; ++nf) {
      const int col = cbase + nf * 16;
#pragma unroll
      for (int j = 0; j < 4; ++j) {
        const int row = rbase + m * 16 + j;
        const size_t idx = (size_t)row * 1024 + col;
        const float z = out[idx];
        const float hv = h[idx];
        const float ht = tanh_f(acc[m][nf][j]);
        out[idx] = z * hv + (1.0f - z) * ht;
      }
    }
  }
}

// ---------- launch ----------
extern "C" void kernel_launch(void* const* d_in, const int* in_sizes, int n_in,
                              void* d_out, int out_size, void* d_ws, size_t ws_size,
                              hipStream_t stream) {
  const float* x   = (const float*)d_in[0];
  const float* h   = (const float*)d_in[1];
  const float* Wwz = (const float*)d_in[2];
  const float* Wuz = (const float*)d_in[3];
  const float* Wwr = (const float*)d_in[4];
  const float* Wur = (const float*)d_in[5];
  const float* Wu  = (const float*)d_in[6];
  const float* Ww  = (const float*)d_in[7];
  float* out = (float*)d_out;

  char* ws = (char*)d_ws;
  u16* xhb = (u16*)(ws);               // 8192*2048*2 = 33,554,432
  u16* A2  = (u16*)(ws + 33554432);    // 8192*2048*2 = 33,554,432
  u16* W1b = (u16*)(ws + 67108864);    // 2048*2048*2 =  8,388,608
  u16* W2b = (u16*)(ws + 75497472);    // 1024*2048*2 =  4,194,304

  pack_xh<<<8192, 256, 0, stream>>>(x, h, xhb, A2);
  pack_W<<<3072, 256, 0, stream>>>(Wwz, Wuz, Wwr, Wur, Wu, Ww, W1b, W2b);
  gemm_zr<<<512, 512, 0, stream>>>(xhb, W1b, h, out, A2);
  gemm2_k<<<256, 512, 0, stream>>>(A2, W2b, h, out);
}

// Round 9
// 284.666 us; speedup vs baseline: 1.2787x; 1.0997x over previous
//
#include <hip/hip_runtime.h>

typedef unsigned short u16;
typedef __attribute__((ext_vector_type(8))) short bf16x8;
typedef __attribute__((ext_vector_type(8))) unsigned short u16x8;
typedef __attribute__((ext_vector_type(4))) float f32x4;

// ---------- helpers ----------
__device__ __forceinline__ u16 f2b(float f) {
  unsigned u = __float_as_uint(f);
  u += 0x7FFFu + ((u >> 16) & 1u);   // RNE to bf16
  return (u16)(u >> 16);
}
__device__ __forceinline__ float sigm(float x) { return 1.0f / (1.0f + __expf(-x)); }
__device__ __forceinline__ float tanh_f(float x) { return 1.0f - 2.0f / (__expf(2.0f * x) + 1.0f); }

__device__ __forceinline__ void cp16(const u16* g, u16* l) {
  __builtin_amdgcn_global_load_lds(
      (const __attribute__((address_space(1))) unsigned int*)g,
      (__attribute__((address_space(3))) unsigned int*)l, 16, 0, 0);
}

__device__ __forceinline__ u16x8 cvt8(float4 a, float4 b) {
  u16x8 v;
  v[0] = f2b(a.x); v[1] = f2b(a.y); v[2] = f2b(a.z); v[3] = f2b(a.w);
  v[4] = f2b(b.x); v[5] = f2b(b.y); v[6] = f2b(b.z); v[7] = f2b(b.w);
  return v;
}

// ---------- pack kernels (R8, proven) ----------
__global__ __launch_bounds__(256) void pack_xh(const float* __restrict__ x,
                                               const float* __restrict__ h,
                                               u16* __restrict__ xhb,
                                               u16* __restrict__ A2) {
  int idx = blockIdx.x * 256 + threadIdx.x;
  int row = idx >> 8;
  int k = (idx & 255) << 3;
  const float* src = (k < 1024) ? (x + (size_t)row * 1024 + k)
                                : (h + (size_t)row * 1024 + (k - 1024));
  float4 a = *reinterpret_cast<const float4*>(src);
  float4 b = *reinterpret_cast<const float4*>(src + 4);
  u16x8 v = cvt8(a, b);
  *reinterpret_cast<u16x8*>(xhb + ((size_t)row << 11) + k) = v;
  if (k < 1024)
    *reinterpret_cast<u16x8*>(A2 + ((size_t)row << 11) + 1024 + k) = v;
}

__global__ __launch_bounds__(256) void pack_W(const float* __restrict__ Wwz,
                                              const float* __restrict__ Wuz,
                                              const float* __restrict__ Wwr,
                                              const float* __restrict__ Wur,
                                              const float* __restrict__ Wu,
                                              const float* __restrict__ Ww,
                                              u16* __restrict__ W1b,
                                              u16* __restrict__ W2b) {
  int idx = blockIdx.x * 256 + threadIdx.x;
  const float* src;
  u16* dst;
  if (idx < 524288) {
    int row = idx >> 8;
    int k = (idx & 255) << 3;
    const float* lo = (row < 1024) ? Wwz : Wwr;
    const float* hi = (row < 1024) ? Wuz : Wur;
    int n = row & 1023;
    src = (k < 1024) ? (lo + (size_t)n * 1024 + k) : (hi + (size_t)n * 1024 + (k - 1024));
    dst = W1b + ((size_t)row << 11) + k;
  } else {
    int j = idx - 524288;
    int row = j >> 8;
    int k = (j & 255) << 3;
    src = (k < 1024) ? (Wu + (size_t)row * 1024 + k) : (Ww + (size_t)row * 1024 + (k - 1024));
    dst = W2b + ((size_t)row << 11) + k;
  }
  float4 a = *reinterpret_cast<const float4*>(src);
  float4 b = *reinterpret_cast<const float4*>(src + 4);
  *reinterpret_cast<u16x8*>(dst) = cvt8(a, b);
}

// ---------- lean co-resident core: 256x128 tile, BK=32, 48KB LDS, 1 barrier/tile ----------
// C[256x128] = A[256xK] @ B[128xK]^T, row-major bf16, pre-offset to tile origin.
// 8 waves = 4M x 2N, wave tile 64x64, acc[4][4]. Linear LDS: A[256][32], B[128][32] u16.
__device__ __forceinline__ void stage_t(const u16* __restrict__ Ag, const u16* __restrict__ Bg,
                                        int lda, int ldb, int T,
                                        u16* Abuf, u16* Bbuf, int arow, int acol, int tid) {
  const u16* ga0 = Ag + (size_t)arow * lda + (size_t)T * 32 + acol;
  cp16(ga0, Abuf + tid * 8);
  cp16(ga0 + (size_t)128 * lda, Abuf + 4096 + tid * 8);
  cp16(Bg + (size_t)arow * ldb + (size_t)T * 32 + acol, Bbuf + tid * 8);
}

__device__ __forceinline__ void mfma_t(const u16* Ar, const u16* Br,
                                       int wr, int wc, int fr, int fk, f32x4 acc[4][4]) {
  bf16x8 af[4], bf[4];
#pragma unroll
  for (int m = 0; m < 4; ++m)
    af[m] = *reinterpret_cast<const bf16x8*>(Ar + (wr * 64 + m * 16 + fr) * 32 + fk);
#pragma unroll
  for (int n = 0; n < 4; ++n)
    bf[n] = *reinterpret_cast<const bf16x8*>(Br + (wc * 64 + n * 16 + fr) * 32 + fk);
#pragma unroll
  for (int m = 0; m < 4; ++m)
#pragma unroll
    for (int n = 0; n < 4; ++n)
      acc[m][n] = __builtin_amdgcn_mfma_f32_16x16x32_bf16(af[m], bf[n], acc[m][n], 0, 0, 0);
}

__device__ __forceinline__ void core(const u16* __restrict__ Ag, const u16* __restrict__ Bg,
                                     int lda, int ldb, int NT,
                                     u16* As0, u16* As1, u16* Bs0, u16* Bs1,
                                     f32x4 acc[4][4]) {
  const int tid = threadIdx.x;
  const int lane = tid & 63;
  const int wid = tid >> 6;
  const int wr = wid >> 1;   // 0..3 (M)
  const int wc = wid & 1;    // 0..1 (N)
  const int arow = tid >> 2;          // staging row (0..127)
  const int acol = (tid & 3) * 8;     // staging u16 col
  const int fr = lane & 15;
  const int fk = (lane >> 4) * 8;

  stage_t(Ag, Bg, lda, ldb, 0, As0, Bs0, arow, acol, tid);
  __syncthreads();

  for (int t = 0; t < NT; t += 2) {
    if (t + 1 < NT) stage_t(Ag, Bg, lda, ldb, t + 1, As1, Bs1, arow, acol, tid);
    mfma_t(As0, Bs0, wr, wc, fr, fk, acc);
    __syncthreads();
    if (t + 2 < NT) stage_t(Ag, Bg, lda, ldb, t + 2, As0, Bs0, arow, acol, tid);
    mfma_t(As1, Bs1, wr, wc, fr, fk, acc);
    __syncthreads();
  }
}

#define CORE_PRE()                                           \
  __shared__ u16 As0[8192];                                  \
  __shared__ u16 As1[8192];                                  \
  __shared__ u16 Bs0[4096];                                  \
  __shared__ u16 Bs1[4096];                                  \
  f32x4 acc[4][4];                                           \
  _Pragma("unroll") for (int m = 0; m < 4; ++m)              \
  _Pragma("unroll") for (int n = 0; n < 4; ++n)              \
      acc[m][n] = (f32x4){0.f, 0.f, 0.f, 0.f};

// GEMM z/r: [8192 x 2048] = xhb @ W1b^T, K=2048. grid 512. z->out, rh->A2 left half.
__global__ __launch_bounds__(512, 4) void gemm_zr(const u16* __restrict__ xhb,
                                                  const u16* __restrict__ W1b,
                                                  const float* __restrict__ h,
                                                  float* __restrict__ zout,
                                                  u16* __restrict__ A2) {
  int b = blockIdx.x;
  int wg = (b & 7) * 64 + (b >> 3);   // XCD chunk of 64 wgs
  int mb = wg >> 4, nb = wg & 15;     // m-major within chunk
  const int m0 = mb * 256, n0 = nb * 128;
  CORE_PRE();
  core(xhb + (size_t)m0 * 2048, W1b + (size_t)n0 * 2048, 2048, 2048, 64,
       As0, As1, Bs0, Bs1, acc);

  const int lane = threadIdx.x & 63;
  const int wid = threadIdx.x >> 6;
  const int wr = wid >> 1, wc = wid & 1;
  const int rbase = m0 + wr * 64 + ((lane >> 4) << 2);
  const int cbase = n0 + wc * 64 + (lane & 15);
  const int isz = (n0 < 1024);
#pragma unroll
  for (int m = 0; m < 4; ++m) {
#pragma unroll
    for (int nf = 0; nf < 4; ++nf) {
      const int col = cbase + nf * 16;
#pragma unroll
      for (int j = 0; j < 4; ++j) {
        const int row = rbase + m * 16 + j;
        const float v = acc[m][nf][j];
        if (isz) {
          zout[(size_t)row * 1024 + col] = sigm(v);
        } else {
          const int c = col - 1024;
          const float rh = sigm(v) * h[(size_t)row * 1024 + c];
          A2[((size_t)row << 11) + c] = f2b(rh);
        }
      }
    }
  }
}

// GEMM2: [8192 x 1024] = A2([rh|x]) @ W2b([Wu|Ww])^T, K=2048. grid 256.
__global__ __launch_bounds__(512, 4) void gemm2_k(const u16* __restrict__ A2,
                                                  const u16* __restrict__ W2b,
                                                  const float* __restrict__ h,
                                                  float* __restrict__ out) {  // holds z
  int b = blockIdx.x;
  int wg = (b & 7) * 32 + (b >> 3);
  int mb = wg >> 3, nb = wg & 7;
  const int m0 = mb * 256, n0 = nb * 128;
  CORE_PRE();
  core(A2 + (size_t)m0 * 2048, W2b + (size_t)n0 * 2048, 2048, 2048, 64,
       As0, As1, Bs0, Bs1, acc);

  const int lane = threadIdx.x & 63;
  const int wid = threadIdx.x >> 6;
  const int wr = wid >> 1, wc = wid & 1;
  const int rbase = m0 + wr * 64 + ((lane >> 4) << 2);
  const int cbase = n0 + wc * 64 + (lane & 15);
#pragma unroll
  for (int m = 0; m < 4; ++m) {
#pragma unroll
    for (int nf = 0; nf < 4; ++nf) {
      const int col = cbase + nf * 16;
#pragma unroll
      for (int j = 0; j < 4; ++j) {
        const int row = rbase + m * 16 + j;
        const size_t idx = (size_t)row * 1024 + col;
        const float z = out[idx];
        const float hv = h[idx];
        const float ht = tanh_f(acc[m][nf][j]);
        out[idx] = z * hv + (1.0f - z) * ht;
      }
    }
  }
}

// ---------- launch ----------
extern "C" void kernel_launch(void* const* d_in, const int* in_sizes, int n_in,
                              void* d_out, int out_size, void* d_ws, size_t ws_size,
                              hipStream_t stream) {
  const float* x   = (const float*)d_in[0];
  const float* h   = (const float*)d_in[1];
  const float* Wwz = (const float*)d_in[2];
  const float* Wuz = (const float*)d_in[3];
  const float* Wwr = (const float*)d_in[4];
  const float* Wur = (const float*)d_in[5];
  const float* Wu  = (const float*)d_in[6];
  const float* Ww  = (const float*)d_in[7];
  float* out = (float*)d_out;

  char* ws = (char*)d_ws;
  u16* xhb = (u16*)(ws);               // 8192*2048*2 = 33,554,432
  u16* A2  = (u16*)(ws + 33554432);    // 8192*2048*2 = 33,554,432
  u16* W1b = (u16*)(ws + 67108864);    // 2048*2048*2 =  8,388,608
  u16* W2b = (u16*)(ws + 75497472);    // 1024*2048*2 =  4,194,304

  pack_xh<<<8192, 256, 0, stream>>>(x, h, xhb, A2);
  pack_W<<<3072, 256, 0, stream>>>(Wwz, Wuz, Wwr, Wur, Wu, Ww, W1b, W2b);
  gemm_zr<<<512, 512, 0, stream>>>(xhb, W1b, h, out, A2);
  gemm2_k<<<256, 512, 0, stream>>>(A2, W2b, h, out);
}